// Round 4
// baseline (111.073 us; speedup 1.0000x reference)
//
#include <hip/hip_runtime.h>

#define T_DIM 256
#define B_DIM 8
#define DIN   256
#define DM    256
#define A_DIM 128
#define NEG_INF_F (-1e30f)
// tanh(x) needs exp(2x); v_exp_f32 computes 2^y -> store projections scaled by 2*log2(e).
#define PRESCALE 2.885390081777927f
#define PROJ_TT 4   // (t,b) rows per proj block
#define CTX_ST  4   // s rows per context block

// ---------------- Kernel A: projections (pre-scaled), 4-row tiled ----------------
// block = 256 threads, handles PROJ_TT consecutive (t,b) rows.
// threads 0..127: a=tid, IP rows; threads 128..255: a=tid-128, MPt rows.
// Each W element is loaded once and reused PROJ_TT times (W L2 traffic /4).
__global__ __launch_bounds__(256) void proj_kernel(
    const float* __restrict__ input, const float* __restrict__ memory,
    const float* __restrict__ Wi, const float* __restrict__ Wm,
    float* __restrict__ IP, float* __restrict__ MPt)
{
    __shared__ float xin[PROJ_TT][DIN];
    __shared__ float xmem[PROJ_TT][DM];
    const int row0 = blockIdx.x * PROJ_TT;           // flat (t*B+b) row index
    const int tid  = threadIdx.x;

    #pragma unroll
    for (int r = 0; r < PROJ_TT; ++r) {
        xin[r][tid]  = input[(row0 + r) * DIN + tid];
        xmem[r][tid] = memory[(row0 + r) * DM + tid];
    }
    __syncthreads();

    if (tid < A_DIM) {
        const int a = tid;
        float acc[PROJ_TT] = {0.f, 0.f, 0.f, 0.f};
        #pragma unroll 8
        for (int d = 0; d < DIN; ++d) {
            const float w = Wi[d * A_DIM + a];
            #pragma unroll
            for (int r = 0; r < PROJ_TT; ++r)
                acc[r] = fmaf(xin[r][d], w, acc[r]);
        }
        #pragma unroll
        for (int r = 0; r < PROJ_TT; ++r)
            IP[(row0 + r) * A_DIM + a] = acc[r] * PRESCALE;
    } else {
        const int a = tid - A_DIM;
        float acc[PROJ_TT] = {0.f, 0.f, 0.f, 0.f};
        #pragma unroll 8
        for (int d = 0; d < DM; ++d) {
            const float w = Wm[d * A_DIM + a];
            #pragma unroll
            for (int r = 0; r < PROJ_TT; ++r)
                acc[r] = fmaf(xmem[r][d], w, acc[r]);
        }
        #pragma unroll
        for (int r = 0; r < PROJ_TT; ++r) {
            const int t = (row0 + r) / B_DIM, b = (row0 + r) % B_DIM;
            MPt[(b * A_DIM + a) * T_DIM + t] = acc[r] * PRESCALE;
        }
    }
}

__device__ inline float warp_red_max(float v) {
    #pragma unroll
    for (int o = 32; o > 0; o >>= 1) v = fmaxf(v, __shfl_xor(v, o, 64));
    return v;
}
__device__ inline float warp_red_sum(float v) {
    #pragma unroll
    for (int o = 32; o > 0; o >>= 1) v += __shfl_xor(v, o, 64);
    return v;
}

// ---------------- Kernel B1: logits + softmax -> SC[s,b,t] ----------------
// block per (s,b): 2048 blocks x 4 waves = 8 blocks/CU = 100% occupancy.
__global__ __launch_bounds__(256) void logits_kernel(
    const int* __restrict__ mask, const float* __restrict__ v,
    const float* __restrict__ IP, const float* __restrict__ MPt,
    float* __restrict__ SC)
{
    __shared__ float ip_s[A_DIM];
    __shared__ float vs[A_DIM];
    __shared__ float red[4];

    const int blk = blockIdx.x;
    const int b   = blk % B_DIM;          // same-b neighbors -> L2 locality for MPt
    const int s   = blk / B_DIM;
    const int tid = threadIdx.x;
    const int lane = tid & 63;
    const int wave = tid >> 6;

    if (tid < A_DIM) {
        vs[tid]   = v[tid];
        ip_s[tid] = IP[(s * B_DIM + b) * A_DIM + tid];
    }
    __syncthreads();

    // logits: thread = key t. v.tanh sum = sumV - 2*sum(v*sigmoid-ish);
    // constant sumV shift cancels in softmax -> logit_eff = -2*acc.
    const int t = tid;
    float acc = 0.f;
    const float* mp_base = MPt + (size_t)(b * A_DIM) * T_DIM + t;
    #pragma unroll 8
    for (int a = 0; a < A_DIM; ++a) {
        const float mp = mp_base[(size_t)a * T_DIM];      // coalesced across t
        const float e  = __builtin_amdgcn_exp2f(ip_s[a] + mp);
        acc = fmaf(vs[a], __builtin_amdgcn_rcpf(e + 1.f), acc);
    }

    const bool valid = (mask[t * B_DIM + b] != 0);
    const float l = valid ? (-2.f * acc) : NEG_INF_F;

    // block softmax over t
    float m = warp_red_max(l);
    if (lane == 0) red[wave] = m;
    __syncthreads();
    m = fmaxf(fmaxf(red[0], red[1]), fmaxf(red[2], red[3]));
    const float e = __expf(l - m);
    float su = warp_red_sum(e);
    __syncthreads();
    if (lane == 0) red[wave] = su;
    __syncthreads();
    su = (red[0] + red[1]) + (red[2] + red[3]);
    SC[(s * B_DIM + b) * T_DIM + t] = e * __builtin_amdgcn_rcpf(su);
}

// ---------------- Kernel B2: context GEMM + concat ----------------
// block per (s-tile of CTX_ST, b): 512 blocks, 256 threads (thread = d).
__global__ __launch_bounds__(256) void context_kernel(
    const float* __restrict__ input, const float* __restrict__ SC,
    float* __restrict__ out)
{
    __shared__ float sc_s[CTX_ST][T_DIM];
    const int blk = blockIdx.x;
    const int b   = blk % B_DIM;
    const int s0  = (blk / B_DIM) * CTX_ST;
    const int tid = threadIdx.x;

    for (int i = tid; i < CTX_ST * T_DIM; i += 256) {
        const int r = i >> 8, t = i & (T_DIM - 1);
        sc_s[r][t] = SC[((s0 + r) * B_DIM + b) * T_DIM + t];
    }
    __syncthreads();

    const int d = tid;
    float c[CTX_ST] = {0.f, 0.f, 0.f, 0.f};
    const float* in_b = input + b * DIN + d;
    #pragma unroll 8
    for (int t2 = 0; t2 < T_DIM; ++t2) {
        const float xv = in_b[(size_t)t2 * B_DIM * DIN];  // coalesced across d
        #pragma unroll
        for (int r = 0; r < CTX_ST; ++r)
            c[r] = fmaf(sc_s[r][t2], xv, c[r]);
    }

    #pragma unroll
    for (int r = 0; r < CTX_ST; ++r) {
        const int row = (s0 + r) * B_DIM + b;
        out[(size_t)row * (2 * DIN) + d]       = c[r];
        out[(size_t)row * (2 * DIN) + DIN + d] = input[row * DIN + d];
    }
}

extern "C" void kernel_launch(void* const* d_in, const int* in_sizes, int n_in,
                              void* d_out, int out_size, void* d_ws, size_t ws_size,
                              hipStream_t stream) {
    const float* input  = (const float*)d_in[0];
    const float* memory = (const float*)d_in[1];
    const int*   mask   = (const int*)d_in[2];
    const float* Wi     = (const float*)d_in[3];
    const float* Wm     = (const float*)d_in[4];
    const float* v      = (const float*)d_in[5];
    float* out = (float*)d_out;

    float* IP  = (float*)d_ws;                           // [T,B,A]  1 MB (pre-scaled)
    float* MPt = IP  + (size_t)T_DIM * B_DIM * A_DIM;    // [B,A,T]  1 MB (pre-scaled)
    float* SC  = MPt + (size_t)B_DIM * A_DIM * T_DIM;    // [T,B,T]  2 MB (softmax scores)

    proj_kernel<<<(T_DIM * B_DIM) / PROJ_TT, 256, 0, stream>>>(input, memory, Wi, Wm, IP, MPt);
    logits_kernel<<<T_DIM * B_DIM, 256, 0, stream>>>(mask, v, IP, MPt, SC);
    context_kernel<<<(T_DIM / CTX_ST) * B_DIM, 256, 0, stream>>>(input, SC, out);
}

// Round 5
// 106.352 us; speedup vs baseline: 1.0444x; 1.0444x over previous
//
#include <hip/hip_runtime.h>

#define T_DIM 256
#define B_DIM 8
#define DIN   256
#define DM    256
#define A_DIM 128
#define NEG_INF_F (-1e30f)
// tanh(x) needs exp(2x); v_exp_f32 computes 2^y -> projections scaled by 2*log2(e),
// and we store EXP2 of the scaled projections (factorized: exp2(ip+mp)=exp2(ip)*exp2(mp)).
#define PRESCALE 2.885390081777927f
#define PROJ_TT 4   // (t,b) rows per proj block
#define CTX_ST  4   // s rows per context block

// ---------------- Kernel A: projections -> EIP=exp2(ip), EM=exp2(mp) ----------------
__global__ __launch_bounds__(256) void proj_kernel(
    const float* __restrict__ input, const float* __restrict__ memory,
    const float* __restrict__ Wi, const float* __restrict__ Wm,
    float* __restrict__ EIP, float* __restrict__ EM)
{
    __shared__ float xin[PROJ_TT][DIN];
    __shared__ float xmem[PROJ_TT][DM];
    const int row0 = blockIdx.x * PROJ_TT;           // flat (t*B+b) row index
    const int tid  = threadIdx.x;

    #pragma unroll
    for (int r = 0; r < PROJ_TT; ++r) {
        xin[r][tid]  = input[(row0 + r) * DIN + tid];
        xmem[r][tid] = memory[(row0 + r) * DM + tid];
    }
    __syncthreads();

    if (tid < A_DIM) {
        const int a = tid;
        float acc[PROJ_TT] = {0.f, 0.f, 0.f, 0.f};
        #pragma unroll 8
        for (int d = 0; d < DIN; ++d) {
            const float w = Wi[d * A_DIM + a];
            #pragma unroll
            for (int r = 0; r < PROJ_TT; ++r)
                acc[r] = fmaf(xin[r][d], w, acc[r]);
        }
        #pragma unroll
        for (int r = 0; r < PROJ_TT; ++r)
            EIP[(row0 + r) * A_DIM + a] =
                __builtin_amdgcn_exp2f(acc[r] * PRESCALE);
    } else {
        const int a = tid - A_DIM;
        float acc[PROJ_TT] = {0.f, 0.f, 0.f, 0.f};
        #pragma unroll 8
        for (int d = 0; d < DM; ++d) {
            const float w = Wm[d * A_DIM + a];
            #pragma unroll
            for (int r = 0; r < PROJ_TT; ++r)
                acc[r] = fmaf(xmem[r][d], w, acc[r]);
        }
        #pragma unroll
        for (int r = 0; r < PROJ_TT; ++r) {
            const int t = (row0 + r) / B_DIM, b = (row0 + r) % B_DIM;
            EM[(b * A_DIM + a) * T_DIM + t] =
                __builtin_amdgcn_exp2f(acc[r] * PRESCALE);
        }
    }
}

__device__ inline float warp_red_max(float v) {
    #pragma unroll
    for (int o = 32; o > 0; o >>= 1) v = fmaxf(v, __shfl_xor(v, o, 64));
    return v;
}
__device__ inline float warp_red_sum(float v) {
    #pragma unroll
    for (int o = 32; o > 0; o >>= 1) v += __shfl_xor(v, o, 64);
    return v;
}

// ---------------- Kernel B1: logits + softmax -> SC[s,b,t] ----------------
// block per (s,b): 2048 blocks x 4 waves = 8 blocks/CU = 100% occupancy.
// Inner item: e = eip[a]*em  (factorized exp2) -> 3 VALU + 1 trans (was 3+2).
__global__ __launch_bounds__(256) void logits_kernel(
    const int* __restrict__ mask, const float* __restrict__ v,
    const float* __restrict__ EIP, const float* __restrict__ EM,
    float* __restrict__ SC)
{
    __shared__ float eip_s[A_DIM];
    __shared__ float vs[A_DIM];
    __shared__ float red[4];

    const int blk = blockIdx.x;
    const int b   = blk % B_DIM;          // same-b neighbors -> same XCD (L2 locality)
    const int s   = blk / B_DIM;
    const int tid = threadIdx.x;
    const int lane = tid & 63;
    const int wave = tid >> 6;

    if (tid < A_DIM) {
        vs[tid]    = v[tid];
        eip_s[tid] = EIP[(s * B_DIM + b) * A_DIM + tid];
    }
    __syncthreads();

    // v.tanh sum = sumV - 2*sum(v * rcp(e+1)); constant sumV cancels in softmax.
    const int t = tid;
    float acc = 0.f;
    const float* em_base = EM + (size_t)(b * A_DIM) * T_DIM + t;
    #pragma unroll 8
    for (int a = 0; a < A_DIM; ++a) {
        const float em = em_base[(size_t)a * T_DIM];      // coalesced across t
        const float e  = eip_s[a] * em;
        acc = fmaf(vs[a], __builtin_amdgcn_rcpf(e + 1.f), acc);
    }

    const bool valid = (mask[t * B_DIM + b] != 0);
    const float l = valid ? (-2.f * acc) : NEG_INF_F;

    // block softmax over t
    float m = warp_red_max(l);
    if (lane == 0) red[wave] = m;
    __syncthreads();
    m = fmaxf(fmaxf(red[0], red[1]), fmaxf(red[2], red[3]));
    const float e = __expf(l - m);
    float su = warp_red_sum(e);
    __syncthreads();
    if (lane == 0) red[wave] = su;
    __syncthreads();
    su = (red[0] + red[1]) + (red[2] + red[3]);
    SC[(s * B_DIM + b) * T_DIM + t] = e * __builtin_amdgcn_rcpf(su);
}

// ---------------- Kernel B2: context GEMM + concat ----------------
// block per (s-tile of CTX_ST, b): 512 blocks, 256 threads (thread = d).
__global__ __launch_bounds__(256) void context_kernel(
    const float* __restrict__ input, const float* __restrict__ SC,
    float* __restrict__ out)
{
    __shared__ float sc_s[CTX_ST][T_DIM];
    const int blk = blockIdx.x;
    const int b   = blk % B_DIM;
    const int s0  = (blk / B_DIM) * CTX_ST;
    const int tid = threadIdx.x;

    for (int i = tid; i < CTX_ST * T_DIM; i += 256) {
        const int r = i >> 8, t = i & (T_DIM - 1);
        sc_s[r][t] = SC[((s0 + r) * B_DIM + b) * T_DIM + t];
    }
    __syncthreads();

    const int d = tid;
    float c[CTX_ST] = {0.f, 0.f, 0.f, 0.f};
    const float* in_b = input + b * DIN + d;
    #pragma unroll 8
    for (int t2 = 0; t2 < T_DIM; ++t2) {
        const float xv = in_b[(size_t)t2 * B_DIM * DIN];  // coalesced across d
        #pragma unroll
        for (int r = 0; r < CTX_ST; ++r)
            c[r] = fmaf(sc_s[r][t2], xv, c[r]);
    }

    #pragma unroll
    for (int r = 0; r < CTX_ST; ++r) {
        const int row = (s0 + r) * B_DIM + b;
        out[(size_t)row * (2 * DIN) + d]       = c[r];
        out[(size_t)row * (2 * DIN) + DIN + d] = input[row * DIN + d];
    }
}

extern "C" void kernel_launch(void* const* d_in, const int* in_sizes, int n_in,
                              void* d_out, int out_size, void* d_ws, size_t ws_size,
                              hipStream_t stream) {
    const float* input  = (const float*)d_in[0];
    const float* memory = (const float*)d_in[1];
    const int*   mask   = (const int*)d_in[2];
    const float* Wi     = (const float*)d_in[3];
    const float* Wm     = (const float*)d_in[4];
    const float* v      = (const float*)d_in[5];
    float* out = (float*)d_out;

    float* EIP = (float*)d_ws;                           // [T,B,A]  1 MB  exp2(ip)
    float* EM  = EIP + (size_t)T_DIM * B_DIM * A_DIM;    // [B,A,T]  1 MB  exp2(mp)
    float* SC  = EM  + (size_t)B_DIM * A_DIM * T_DIM;    // [T,B,T]  2 MB  softmax scores

    proj_kernel<<<(T_DIM * B_DIM) / PROJ_TT, 256, 0, stream>>>(input, memory, Wi, Wm, EIP, EM);
    logits_kernel<<<T_DIM * B_DIM, 256, 0, stream>>>(mask, v, EIP, EM, SC);
    context_kernel<<<(T_DIM / CTX_ST) * B_DIM, 256, 0, stream>>>(input, SC, out);
}

// Round 6
// 101.469 us; speedup vs baseline: 1.0946x; 1.0481x over previous
//
#include <hip/hip_runtime.h>

#define T_DIM 256
#define B_DIM 8
#define DIN   256
#define DM    256
#define A_DIM 128
#define NEG_INF_F (-1e30f)
// tanh(x) needs exp(2x); v_exp_f32 computes 2^y -> projections scaled by 2*log2(e),
// and we store EXP2 of the scaled projections (factorized: exp2(ip+mp)=exp2(ip)*exp2(mp)).
#define PRESCALE 2.885390081777927f
#define PROJ_TT 4   // (t,b) rows per proj block
#define S_PAIR  2   // s rows per fused-attention block

// ---------------- Kernel A: projections -> EIP=exp2(ip), EM=exp2(mp) ----------------
__global__ __launch_bounds__(256) void proj_kernel(
    const float* __restrict__ input, const float* __restrict__ memory,
    const float* __restrict__ Wi, const float* __restrict__ Wm,
    float* __restrict__ EIP, float* __restrict__ EM)
{
    __shared__ float xin[PROJ_TT][DIN];
    __shared__ float xmem[PROJ_TT][DM];
    const int row0 = blockIdx.x * PROJ_TT;           // flat (t*B+b) row index
    const int tid  = threadIdx.x;

    #pragma unroll
    for (int r = 0; r < PROJ_TT; ++r) {
        xin[r][tid]  = input[(row0 + r) * DIN + tid];
        xmem[r][tid] = memory[(row0 + r) * DM + tid];
    }
    __syncthreads();

    if (tid < A_DIM) {
        const int a = tid;
        float acc[PROJ_TT] = {0.f, 0.f, 0.f, 0.f};
        #pragma unroll 8
        for (int d = 0; d < DIN; ++d) {
            const float w = Wi[d * A_DIM + a];
            #pragma unroll
            for (int r = 0; r < PROJ_TT; ++r)
                acc[r] = fmaf(xin[r][d], w, acc[r]);
        }
        #pragma unroll
        for (int r = 0; r < PROJ_TT; ++r)
            EIP[(row0 + r) * A_DIM + a] =
                __builtin_amdgcn_exp2f(acc[r] * PRESCALE);
    } else {
        const int a = tid - A_DIM;
        float acc[PROJ_TT] = {0.f, 0.f, 0.f, 0.f};
        #pragma unroll 8
        for (int d = 0; d < DM; ++d) {
            const float w = Wm[d * A_DIM + a];
            #pragma unroll
            for (int r = 0; r < PROJ_TT; ++r)
                acc[r] = fmaf(xmem[r][d], w, acc[r]);
        }
        #pragma unroll
        for (int r = 0; r < PROJ_TT; ++r) {
            const int t = (row0 + r) / B_DIM, b = (row0 + r) % B_DIM;
            EM[(b * A_DIM + a) * T_DIM + t] =
                __builtin_amdgcn_exp2f(acc[r] * PRESCALE);
        }
    }
}

__device__ inline float warp_red_max(float v) {
    #pragma unroll
    for (int o = 32; o > 0; o >>= 1) v = fmaxf(v, __shfl_xor(v, o, 64));
    return v;
}
__device__ inline float warp_red_sum(float v) {
    #pragma unroll
    for (int o = 32; o > 0; o >>= 1) v += __shfl_xor(v, o, 64);
    return v;
}

// ---------------- Kernel B: fused logits + softmax + context + concat ----------------
// block per (s-pair, b): 1024 blocks x 4 waves = 4 blocks/CU (16 waves/CU).
// Phase 1: thread = key t; one EM load feeds both s rows.
// Phase 2: thread = feature d; sc stays in LDS (no SC round-trip to memory).
__global__ __launch_bounds__(256) void attn_kernel(
    const float* __restrict__ input, const int* __restrict__ mask,
    const float* __restrict__ v, const float* __restrict__ EIP,
    const float* __restrict__ EM, float* __restrict__ out)
{
    __shared__ float eip_s[S_PAIR][A_DIM];
    __shared__ float vs[A_DIM];
    __shared__ float sc[S_PAIR][T_DIM];
    __shared__ float redm[S_PAIR][4];

    const int blk = blockIdx.x;
    const int b   = blk % B_DIM;          // same-b neighbors -> L2 locality for EM/input
    const int s0  = (blk / B_DIM) * S_PAIR;
    const int tid = threadIdx.x;
    const int lane = tid & 63;
    const int wave = tid >> 6;

    if (tid < A_DIM) {
        vs[tid]          = v[tid];
        eip_s[0][tid]    = EIP[((s0 + 0) * B_DIM + b) * A_DIM + tid];
        eip_s[1][tid]    = EIP[((s0 + 1) * B_DIM + b) * A_DIM + tid];
    }
    __syncthreads();

    // ---- Phase 1: logits. v.tanh sum = sumV - 2*sum(v*rcp(e+1)); sumV cancels
    // in softmax -> logit_eff = -2*acc.
    const int t = tid;
    float acc0 = 0.f, acc1 = 0.f;
    const float* em_base = EM + (size_t)(b * A_DIM) * T_DIM + t;
    #pragma unroll 8
    for (int a = 0; a < A_DIM; ++a) {
        const float em = em_base[(size_t)a * T_DIM];      // coalesced across t
        const float va = vs[a];
        const float e0 = eip_s[0][a] * em;
        const float e1 = eip_s[1][a] * em;
        acc0 = fmaf(va, __builtin_amdgcn_rcpf(e0 + 1.f), acc0);
        acc1 = fmaf(va, __builtin_amdgcn_rcpf(e1 + 1.f), acc1);
    }

    const bool valid = (mask[t * B_DIM + b] != 0);
    const float l0 = valid ? (-2.f * acc0) : NEG_INF_F;
    const float l1 = valid ? (-2.f * acc1) : NEG_INF_F;

    // ---- softmax over t, both s rows fused ----
    float m0 = warp_red_max(l0), m1 = warp_red_max(l1);
    if (lane == 0) { redm[0][wave] = m0; redm[1][wave] = m1; }
    __syncthreads();
    m0 = fmaxf(fmaxf(redm[0][0], redm[0][1]), fmaxf(redm[0][2], redm[0][3]));
    m1 = fmaxf(fmaxf(redm[1][0], redm[1][1]), fmaxf(redm[1][2], redm[1][3]));
    const float e0 = __expf(l0 - m0);
    const float e1 = __expf(l1 - m1);
    float su0 = warp_red_sum(e0), su1 = warp_red_sum(e1);
    __syncthreads();
    if (lane == 0) { redm[0][wave] = su0; redm[1][wave] = su1; }
    __syncthreads();
    su0 = (redm[0][0] + redm[0][1]) + (redm[0][2] + redm[0][3]);
    su1 = (redm[1][0] + redm[1][1]) + (redm[1][2] + redm[1][3]);
    sc[0][t] = e0 * __builtin_amdgcn_rcpf(su0);
    sc[1][t] = e1 * __builtin_amdgcn_rcpf(su1);
    __syncthreads();

    // ---- Phase 2: context. thread = feature d. ----
    const int d = tid;
    float c0 = 0.f, c1 = 0.f;
    const float* in_b = input + b * DIN + d;
    #pragma unroll 8
    for (int t2 = 0; t2 < T_DIM; ++t2) {
        const float xv = in_b[(size_t)t2 * B_DIM * DIN];  // coalesced across d
        c0 = fmaf(sc[0][t2], xv, c0);
        c1 = fmaf(sc[1][t2], xv, c1);
    }

    {
        const int r0 = (s0 + 0) * B_DIM + b;
        const int r1 = (s0 + 1) * B_DIM + b;
        out[(size_t)r0 * (2 * DIN) + d]       = c0;
        out[(size_t)r0 * (2 * DIN) + DIN + d] = input[r0 * DIN + d];
        out[(size_t)r1 * (2 * DIN) + d]       = c1;
        out[(size_t)r1 * (2 * DIN) + DIN + d] = input[r1 * DIN + d];
    }
}

extern "C" void kernel_launch(void* const* d_in, const int* in_sizes, int n_in,
                              void* d_out, int out_size, void* d_ws, size_t ws_size,
                              hipStream_t stream) {
    const float* input  = (const float*)d_in[0];
    const float* memory = (const float*)d_in[1];
    const int*   mask   = (const int*)d_in[2];
    const float* Wi     = (const float*)d_in[3];
    const float* Wm     = (const float*)d_in[4];
    const float* v      = (const float*)d_in[5];
    float* out = (float*)d_out;

    float* EIP = (float*)d_ws;                           // [T,B,A]  1 MB  exp2(ip)
    float* EM  = EIP + (size_t)T_DIM * B_DIM * A_DIM;    // [B,A,T]  1 MB  exp2(mp)

    proj_kernel<<<(T_DIM * B_DIM) / PROJ_TT, 256, 0, stream>>>(input, memory, Wi, Wm, EIP, EM);
    attn_kernel<<<(T_DIM / S_PAIR) * B_DIM, 256, 0, stream>>>(input, mask, v, EIP, EM, out);
}